// Round 5
// baseline (398.981 us; speedup 1.0000x reference)
//
#include <hip/hip_runtime.h>
#include <hip/hip_bf16.h>

#define N_NODES 50000
#define N_EDGES 800000
#define IN_C 512
#define HID_C 256
#define OUT_C 128
#define SCAN_BLOCKS 49  // ceil(50000 / 1024)

typedef short bf16x8 __attribute__((ext_vector_type(8)));
typedef float f32x4 __attribute__((ext_vector_type(4)));
typedef float f32x2 __attribute__((ext_vector_type(2)));

__device__ __forceinline__ float bf2f(unsigned short u) {
    return __uint_as_float(((unsigned)u) << 16);
}
__device__ __forceinline__ unsigned short f2bf(float f) {
    __hip_bfloat16 h = __float2bfloat16(f);
    return *(unsigned short*)&h;
}
// decode 4 fp8(e4m3) from one dword, accumulate (unweighted) into a[0..3]
__device__ __forceinline__ void acc_fp8x4(int dw, float* a) {
    f32x2 lo = __builtin_amdgcn_cvt_pk_f32_fp8(dw, false);
    f32x2 hi = __builtin_amdgcn_cvt_pk_f32_fp8(dw, true);
    a[0] += lo[0]; a[1] += lo[1]; a[2] += hi[0]; a[3] += hi[1];
}
__device__ __forceinline__ unsigned char f2fp8(float f) {
    return (unsigned char)(__builtin_amdgcn_cvt_pk_fp8_f32(f, 0.0f, 0, false) & 0xff);
}

// ---------------------------------------------------------------- CSR build
__global__ void zero_counts_kernel(int* __restrict__ counts) {
    int i = blockIdx.x * blockDim.x + threadIdx.x;
    if (i < N_NODES) counts[i] = 0;
}

__global__ void count_kernel(const int* __restrict__ ei, int* __restrict__ counts) {
    int e = blockIdx.x * blockDim.x + threadIdx.x;
    if (e < N_EDGES) atomicAdd(&counts[ei[N_EDGES + e]], 1);
}

__global__ __launch_bounds__(256) void scan_part_kernel(const int* __restrict__ counts,
                                                        int* __restrict__ excl,
                                                        int* __restrict__ bsums) {
    __shared__ int tsum[256];
    const int t = threadIdx.x;
    const int base = blockIdx.x * 1024 + t * 4;
    int v[4];
    int s = 0;
#pragma unroll
    for (int j = 0; j < 4; j++) {
        int idx = base + j;
        v[j] = (idx < N_NODES) ? counts[idx] : 0;
        s += v[j];
    }
    tsum[t] = s;
    __syncthreads();
    for (int off = 1; off < 256; off <<= 1) {
        int add = (t >= off) ? tsum[t - off] : 0;
        __syncthreads();
        tsum[t] += add;
        __syncthreads();
    }
    int run = tsum[t] - s;
#pragma unroll
    for (int j = 0; j < 4; j++) {
        int idx = base + j;
        if (idx < N_NODES) excl[idx] = run;
        run += v[j];
    }
    if (t == 255) bsums[blockIdx.x] = tsum[255];
}

// wave-parallel exclusive scan of the 49 block sums
__global__ void scan_sums_kernel(int* __restrict__ bsums) {
    int ln = threadIdx.x;  // 64 threads = 1 wave
    int v = (ln < SCAN_BLOCKS) ? bsums[ln] : 0;
    for (int off = 1; off < 64; off <<= 1) {
        int u = __shfl_up(v, off, 64);
        if (ln >= off) v += u;
    }
    int excl = __shfl_up(v, 1, 64);
    if (ln == 0) excl = 0;
    if (ln < SCAN_BLOCKS) bsums[ln] = excl;
}

__global__ void add_dinv_kernel(int* __restrict__ offsets, const int* __restrict__ bsums,
                                int* __restrict__ woff, const int* __restrict__ counts,
                                float* __restrict__ dinv) {
    int i = blockIdx.x * blockDim.x + threadIdx.x;
    if (i < N_NODES) {
        int o = offsets[i] + bsums[i >> 10];
        offsets[i] = o;
        woff[i] = o;
        dinv[i] = rsqrtf(1.0f + (float)counts[i]);
    }
    if (i == 0) offsets[N_NODES] = N_EDGES;
}

// edge record is just src (4B): norm is folded into prescaled rows (GEMM
// epilogues scale row r by dinv[r]) and the dst factor applied at gather end.
__global__ void fill_kernel(const int* __restrict__ ei, int* __restrict__ woff,
                            int* __restrict__ sedge) {
    int e = blockIdx.x * blockDim.x + threadIdx.x;
    if (e < N_EDGES) {
        int s = ei[e];
        int d = ei[N_EDGES + e];
        int pos = atomicAdd(&woff[d], 1);
        sedge[pos] = s;
    }
}

// --------------------------------------------------------------- W packing
// Pack W[K][N] (fp32) into MFMA-fragment-major bf16:
// Bp[((t*NT + nt)*64 + ln)*8 + j] = bf16( W[k][n] ),
//   k = t*32 + (ln>>4)*8 + j, n = nt*16 + (ln&15), NT = N/16.
// A wave then fetches B-frag (t,nt) as ONE coalesced 1KB global_load_dwordx4
// (lane ln reads its 16B at offset ln*16 -> perfectly contiguous).
__global__ __launch_bounds__(256) void pack_w_kernel(const float* __restrict__ W,
                                                     unsigned short* __restrict__ Bp,
                                                     int N) {
    int idx = blockIdx.x * 256 + threadIdx.x;  // grid covers K*N exactly
    int j = idx & 7;
    int ln = (idx >> 3) & 63;
    int rest = idx >> 9;  // t*NT + nt
    int NT = N >> 4;
    int nt = rest % NT, t = rest / NT;
    int k = t * 32 + (ln >> 4) * 8 + j;
    int n = nt * 16 + (ln & 15);
    Bp[idx] = f2bf(W[(size_t)k * N + n]);
}

// --------------------------------------- barrier-free all-register GEMM 1
// H1[M,256](fp8) = fp8( dinv[row] * (bf16(x[M,512]) @ W1^T) )
// 4 waves/block; wave w owns rows [64*blk+16w, +16), ALL 256 cols.
// A: per-lane 32B fp32 load -> cvt -> bf16x8 fragment (x read exactly once).
// B: fragment-major packed; one coalesced 1KB load per (step, col-tile),
//    identical across waves -> L1 broadcast. NO LDS, NO BARRIERS: waves slip
//    freely, compiler emits counted per-wave vmcnt (no vmcnt(0) drain).
__global__ __launch_bounds__(256) void gemm1_rf(const float* __restrict__ x,
                                                const unsigned short* __restrict__ Bp,
                                                unsigned char* __restrict__ C,
                                                const float* __restrict__ dinv) {
    const int w = threadIdx.x >> 6;
    const int ln = threadIdx.x & 63;
    const int quad = ln >> 4;
    const int l16 = ln & 15;
    const int rbase = blockIdx.x * 64 + w * 16;

    int arow = rbase + l16;
    arow = arow < N_NODES ? arow : N_NODES - 1;  // clamp (stores guarded)
    const float* xr = x + (size_t)arow * IN_C + quad * 8;
    const unsigned short* bl = Bp + ln * 8;

    f32x4 acc[16];
#pragma unroll
    for (int nt = 0; nt < 16; nt++) acc[nt] = (f32x4){0.f, 0.f, 0.f, 0.f};

    for (int t = 0; t < 16; t++) {
        float4 v0 = *(const float4*)(xr + t * 32);
        float4 v1 = *(const float4*)(xr + t * 32 + 4);
        bf16x8 a8;
        a8[0] = (short)f2bf(v0.x); a8[1] = (short)f2bf(v0.y);
        a8[2] = (short)f2bf(v0.z); a8[3] = (short)f2bf(v0.w);
        a8[4] = (short)f2bf(v1.x); a8[5] = (short)f2bf(v1.y);
        a8[6] = (short)f2bf(v1.z); a8[7] = (short)f2bf(v1.w);
        const unsigned short* bs = bl + t * 16 * 512;
#pragma unroll
        for (int h = 0; h < 2; h++) {  // two halves of 8 col-tiles (VGPR cap)
            bf16x8 b0 = *(const bf16x8*)(bs + (h * 8 + 0) * 512);
            bf16x8 b1 = *(const bf16x8*)(bs + (h * 8 + 1) * 512);
            bf16x8 b2 = *(const bf16x8*)(bs + (h * 8 + 2) * 512);
            bf16x8 b3 = *(const bf16x8*)(bs + (h * 8 + 3) * 512);
            bf16x8 b4 = *(const bf16x8*)(bs + (h * 8 + 4) * 512);
            bf16x8 b5 = *(const bf16x8*)(bs + (h * 8 + 5) * 512);
            bf16x8 b6 = *(const bf16x8*)(bs + (h * 8 + 6) * 512);
            bf16x8 b7 = *(const bf16x8*)(bs + (h * 8 + 7) * 512);
            acc[h * 8 + 0] = __builtin_amdgcn_mfma_f32_16x16x32_bf16(a8, b0, acc[h * 8 + 0], 0, 0, 0);
            acc[h * 8 + 1] = __builtin_amdgcn_mfma_f32_16x16x32_bf16(a8, b1, acc[h * 8 + 1], 0, 0, 0);
            acc[h * 8 + 2] = __builtin_amdgcn_mfma_f32_16x16x32_bf16(a8, b2, acc[h * 8 + 2], 0, 0, 0);
            acc[h * 8 + 3] = __builtin_amdgcn_mfma_f32_16x16x32_bf16(a8, b3, acc[h * 8 + 3], 0, 0, 0);
            acc[h * 8 + 4] = __builtin_amdgcn_mfma_f32_16x16x32_bf16(a8, b4, acc[h * 8 + 4], 0, 0, 0);
            acc[h * 8 + 5] = __builtin_amdgcn_mfma_f32_16x16x32_bf16(a8, b5, acc[h * 8 + 5], 0, 0, 0);
            acc[h * 8 + 6] = __builtin_amdgcn_mfma_f32_16x16x32_bf16(a8, b6, acc[h * 8 + 6], 0, 0, 0);
            acc[h * 8 + 7] = __builtin_amdgcn_mfma_f32_16x16x32_bf16(a8, b7, acc[h * 8 + 7], 0, 0, 0);
        }
    }

#pragma unroll
    for (int r = 0; r < 4; r++) {
        int gr = rbase + quad * 4 + r;
        if (gr < N_NODES) {
            float ds = dinv[gr];
#pragma unroll
            for (int nt = 0; nt < 16; nt++)
                C[(size_t)gr * HID_C + nt * 16 + l16] = f2fp8(ds * acc[nt][r]);
        }
    }
}

// --------------------------------------- barrier-free all-register GEMM 2
// H2[M,128](bf16) = bf16( dinv[row] * (A1b[M,256](bf16) @ W2^T) )
__global__ __launch_bounds__(256) void gemm2_rf(const unsigned short* __restrict__ A,
                                                const unsigned short* __restrict__ Bp,
                                                unsigned short* __restrict__ C,
                                                const float* __restrict__ dinv) {
    const int w = threadIdx.x >> 6;
    const int ln = threadIdx.x & 63;
    const int quad = ln >> 4;
    const int l16 = ln & 15;
    const int rbase = blockIdx.x * 64 + w * 16;

    int arow = rbase + l16;
    arow = arow < N_NODES ? arow : N_NODES - 1;
    const unsigned short* ar = A + (size_t)arow * HID_C + quad * 8;
    const unsigned short* bl = Bp + ln * 8;

    f32x4 acc[8];
#pragma unroll
    for (int nt = 0; nt < 8; nt++) acc[nt] = (f32x4){0.f, 0.f, 0.f, 0.f};

    for (int t = 0; t < 8; t++) {
        bf16x8 a8 = *(const bf16x8*)(ar + t * 32);
        const unsigned short* bs = bl + t * 8 * 512;
        bf16x8 b0 = *(const bf16x8*)(bs + 0 * 512);
        bf16x8 b1 = *(const bf16x8*)(bs + 1 * 512);
        bf16x8 b2 = *(const bf16x8*)(bs + 2 * 512);
        bf16x8 b3 = *(const bf16x8*)(bs + 3 * 512);
        bf16x8 b4 = *(const bf16x8*)(bs + 4 * 512);
        bf16x8 b5 = *(const bf16x8*)(bs + 5 * 512);
        bf16x8 b6 = *(const bf16x8*)(bs + 6 * 512);
        bf16x8 b7 = *(const bf16x8*)(bs + 7 * 512);
        acc[0] = __builtin_amdgcn_mfma_f32_16x16x32_bf16(a8, b0, acc[0], 0, 0, 0);
        acc[1] = __builtin_amdgcn_mfma_f32_16x16x32_bf16(a8, b1, acc[1], 0, 0, 0);
        acc[2] = __builtin_amdgcn_mfma_f32_16x16x32_bf16(a8, b2, acc[2], 0, 0, 0);
        acc[3] = __builtin_amdgcn_mfma_f32_16x16x32_bf16(a8, b3, acc[3], 0, 0, 0);
        acc[4] = __builtin_amdgcn_mfma_f32_16x16x32_bf16(a8, b4, acc[4], 0, 0, 0);
        acc[5] = __builtin_amdgcn_mfma_f32_16x16x32_bf16(a8, b5, acc[5], 0, 0, 0);
        acc[6] = __builtin_amdgcn_mfma_f32_16x16x32_bf16(a8, b6, acc[6], 0, 0, 0);
        acc[7] = __builtin_amdgcn_mfma_f32_16x16x32_bf16(a8, b7, acc[7], 0, 0, 0);
    }

#pragma unroll
    for (int r = 0; r < 4; r++) {
        int gr = rbase + quad * 4 + r;
        if (gr < N_NODES) {
            float ds = dinv[gr];
#pragma unroll
            for (int nt = 0; nt < 8; nt++)
                C[(size_t)gr * OUT_C + nt * 16 + l16] = f2bf(ds * acc[nt][r]);
        }
    }
}

// ------------------------------------------------------- gather aggregation
// Layer-1 gather: H rows are fp8(e4m3), prescaled by dinv[src]. One wave per
// node, 2 groups of 32 lanes; lane covers 8 channels (8B fp8 load).
// out = bf16( relu( dinv[node] * (self' + sum_e row'[src]) + bias ) )
__global__ __launch_bounds__(256) void gather1_fp8(const int* __restrict__ offsets,
                                                   const int* __restrict__ sedge,
                                                   const unsigned char* __restrict__ H,
                                                   const float* __restrict__ dinv,
                                                   const float* __restrict__ bias,
                                                   unsigned short* __restrict__ out) {
    const int node = blockIdx.x * 4 + (threadIdx.x >> 6);
    if (node >= N_NODES) return;
    const int ln = threadIdx.x & 63;
    const int g = ln >> 5;   // 2 groups
    const int l = ln & 31;
    const int c0 = l * 8;

    float acc[8] = {};
    if (g == 0) {  // self term exactly once (row already has dinv[node] folded)
        uint2 d = *(const uint2*)&H[(size_t)node * HID_C + c0];
        acc_fp8x4((int)d.x, acc);
        acc_fp8x4((int)d.y, acc + 4);
    }

    int k = offsets[node] + g;
    const int k1 = offsets[node + 1];
    for (; k + 6 < k1; k += 8) {  // 4-deep unroll, group stride 2
        int s0 = sedge[k], s1 = sedge[k + 2], s2 = sedge[k + 4], s3 = sedge[k + 6];
        uint2 d0 = *(const uint2*)&H[(size_t)s0 * HID_C + c0];
        uint2 d1 = *(const uint2*)&H[(size_t)s1 * HID_C + c0];
        uint2 d2 = *(const uint2*)&H[(size_t)s2 * HID_C + c0];
        uint2 d3 = *(const uint2*)&H[(size_t)s3 * HID_C + c0];
        acc_fp8x4((int)d0.x, acc); acc_fp8x4((int)d0.y, acc + 4);
        acc_fp8x4((int)d1.x, acc); acc_fp8x4((int)d1.y, acc + 4);
        acc_fp8x4((int)d2.x, acc); acc_fp8x4((int)d2.y, acc + 4);
        acc_fp8x4((int)d3.x, acc); acc_fp8x4((int)d3.y, acc + 4);
    }
    for (; k < k1; k += 2) {
        int s0 = sedge[k];
        uint2 d0 = *(const uint2*)&H[(size_t)s0 * HID_C + c0];
        acc_fp8x4((int)d0.x, acc);
        acc_fp8x4((int)d0.y, acc + 4);
    }

    // combine the 2 group partials
#pragma unroll
    for (int j = 0; j < 8; j++) acc[j] += __shfl_xor(acc[j], 32, 64);

    if (g == 0) {
        const float di = dinv[node];
        bf16x8 o;
#pragma unroll
        for (int j = 0; j < 8; j++)
            o[j] = (short)f2bf(fmaxf(di * acc[j] + bias[c0 + j], 0.0f));
        *(bf16x8*)&out[(size_t)node * HID_C + c0] = o;
    }
}

// Layer-2 gather: H rows bf16, prescaled by dinv[src]. 4 groups of 16 lanes;
// lane covers 8 channels (16B bf16 load). fp32 output.
__global__ __launch_bounds__(256) void gather2_bf16(const int* __restrict__ offsets,
                                                    const int* __restrict__ sedge,
                                                    const unsigned short* __restrict__ H,
                                                    const float* __restrict__ dinv,
                                                    const float* __restrict__ bias,
                                                    float* __restrict__ out) {
    const int node = blockIdx.x * 4 + (threadIdx.x >> 6);
    if (node >= N_NODES) return;
    const int ln = threadIdx.x & 63;
    const int g = ln >> 4;   // 4 groups
    const int l = ln & 15;
    const int c0 = l * 8;

    float acc[8] = {};
    if (g == 0) {
        bf16x8 h = *(const bf16x8*)&H[(size_t)node * OUT_C + c0];
#pragma unroll
        for (int j = 0; j < 8; j++) acc[j] = bf2f((unsigned short)h[j]);
    }

    int k = offsets[node] + g;
    const int k1 = offsets[node + 1];
    for (; k + 12 < k1; k += 16) {  // 4-deep unroll, group stride 4
        int s0 = sedge[k], s1 = sedge[k + 4], s2 = sedge[k + 8], s3 = sedge[k + 12];
        bf16x8 h0 = *(const bf16x8*)&H[(size_t)s0 * OUT_C + c0];
        bf16x8 h1 = *(const bf16x8*)&H[(size_t)s1 * OUT_C + c0];
        bf16x8 h2 = *(const bf16x8*)&H[(size_t)s2 * OUT_C + c0];
        bf16x8 h3 = *(const bf16x8*)&H[(size_t)s3 * OUT_C + c0];
#pragma unroll
        for (int j = 0; j < 8; j++) {
            acc[j] += bf2f((unsigned short)h0[j]);
            acc[j] += bf2f((unsigned short)h1[j]);
            acc[j] += bf2f((unsigned short)h2[j]);
            acc[j] += bf2f((unsigned short)h3[j]);
        }
    }
    for (; k < k1; k += 4) {
        int s0 = sedge[k];
        bf16x8 h0 = *(const bf16x8*)&H[(size_t)s0 * OUT_C + c0];
#pragma unroll
        for (int j = 0; j < 8; j++) acc[j] += bf2f((unsigned short)h0[j]);
    }

#pragma unroll
    for (int m = 16; m < 64; m <<= 1) {
#pragma unroll
        for (int j = 0; j < 8; j++) acc[j] += __shfl_xor(acc[j], m, 64);
    }

    if (g == 0) {
        const float di = dinv[node];
        float o[8];
#pragma unroll
        for (int j = 0; j < 8; j++) o[j] = di * acc[j] + bias[c0 + j];
        *(float4*)&out[(size_t)node * OUT_C + c0] = make_float4(o[0], o[1], o[2], o[3]);
        *(float4*)&out[(size_t)node * OUT_C + c0 + 4] = make_float4(o[4], o[5], o[6], o[7]);
    }
}

// ---------------------------------------------------------------- launcher
extern "C" void kernel_launch(void* const* d_in, const int* in_sizes, int n_in,
                              void* d_out, int out_size, void* d_ws, size_t ws_size,
                              hipStream_t stream) {
    const float* x  = (const float*)d_in[0];
    const int*   ei = (const int*)d_in[1];
    const float* W1 = (const float*)d_in[2];
    const float* b1 = (const float*)d_in[3];
    const float* W2 = (const float*)d_in[4];
    const float* b2 = (const float*)d_in[5];
    float* out = (float*)d_out;

    // workspace layout (4-byte words), same as known-good R2 (68.3 MiB).
    int*   counts     = (int*)d_ws;                          // 50048
    int*   offsets    = counts + 50048;                      // 50052 (+sentinel)
    int*   woff       = offsets + 50052;                     // 50048
    int*   bsums      = woff + 50048;                        // 64
    float* dinv       = (float*)(bsums + 64);                // 50048
    int*   sedge      = (int*)(dinv + 50048);                // 800000 (src only)
    unsigned short* Bp1 = (unsigned short*)(sedge + 800000);          // 131072 sh (16B-aligned)
    unsigned short* Bp2 = Bp1 + 131072;                               // 32768 sh
    unsigned short* xb  = Bp2 + 32768;                                // 25.6M sh region
    unsigned char*  H1  = (unsigned char*)(xb + (size_t)N_NODES * IN_C);  // 12.8MB fp8
    unsigned short* A1b = xb;                                         // overlay
    unsigned short* H2  = xb + (size_t)N_NODES * HID_C;               // overlay

    // CSR build + norm
    zero_counts_kernel<<<(N_NODES + 255) / 256, 256, 0, stream>>>(counts);
    count_kernel<<<(N_EDGES + 255) / 256, 256, 0, stream>>>(ei, counts);
    scan_part_kernel<<<SCAN_BLOCKS, 256, 0, stream>>>(counts, offsets, bsums);
    scan_sums_kernel<<<1, 64, 0, stream>>>(bsums);
    add_dinv_kernel<<<(N_NODES + 255) / 256, 256, 0, stream>>>(offsets, bsums, woff, counts, dinv);
    fill_kernel<<<(N_EDGES + 255) / 256, 256, 0, stream>>>(ei, woff, sedge);

    // weight packs (fragment-major bf16; tiny)
    pack_w_kernel<<<(IN_C * HID_C) / 256, 256, 0, stream>>>(W1, Bp1, HID_C);
    pack_w_kernel<<<(HID_C * OUT_C) / 256, 256, 0, stream>>>(W2, Bp2, OUT_C);

    // layer 1: H1 = fp8( dinv[row] * (bf16(x) @ W1^T) )  (no-LDS, no-barrier)
    gemm1_rf<<<(N_NODES + 63) / 64, 256, 0, stream>>>(x, Bp1, H1, dinv);
    gather1_fp8<<<(N_NODES + 3) / 4, 256, 0, stream>>>(offsets, sedge, H1, dinv, b1, A1b);

    // layer 2: H2 = bf16( dinv[row] * (A1b @ W2^T) )
    gemm2_rf<<<(N_NODES + 63) / 64, 256, 0, stream>>>(A1b, Bp2, H2, dinv);
    gather2_bf16<<<(N_NODES + 3) / 4, 256, 0, stream>>>(offsets, sedge, H2, dinv, b2, out);
}

// Round 7
// 394.095 us; speedup vs baseline: 1.0124x; 1.0124x over previous
//
#include <hip/hip_runtime.h>
#include <hip/hip_bf16.h>

#define N_NODES 50000
#define N_EDGES 800000
#define IN_C 512
#define HID_C 256
#define OUT_C 128
#define SCAN_BLOCKS 49  // ceil(50000 / 1024)

typedef short bf16x8 __attribute__((ext_vector_type(8)));
typedef float f32x4 __attribute__((ext_vector_type(4)));
typedef float f32x2 __attribute__((ext_vector_type(2)));

__device__ __forceinline__ float bf2f(unsigned short u) {
    return __uint_as_float(((unsigned)u) << 16);
}
__device__ __forceinline__ unsigned short f2bf(float f) {
    __hip_bfloat16 h = __float2bfloat16(f);
    return *(unsigned short*)&h;
}
// decode 4 fp8(e4m3) from one dword, accumulate (unweighted) into a[0..3]
__device__ __forceinline__ void acc_fp8x4(int dw, float* a) {
    f32x2 lo = __builtin_amdgcn_cvt_pk_f32_fp8(dw, false);
    f32x2 hi = __builtin_amdgcn_cvt_pk_f32_fp8(dw, true);
    a[0] += lo[0]; a[1] += lo[1]; a[2] += hi[0]; a[3] += hi[1];
}
__device__ __forceinline__ unsigned char f2fp8(float f) {
    return (unsigned char)(__builtin_amdgcn_cvt_pk_fp8_f32(f, 0.0f, 0, false) & 0xff);
}
__device__ __forceinline__ void glds16(const void* gp, void* lp) {
    __builtin_amdgcn_global_load_lds((const __attribute__((address_space(1))) void*)gp,
                                     (__attribute__((address_space(3))) void*)lp, 16, 0, 0);
}

// ---------------------------------------------------------------- CSR build
__global__ void zero_counts_kernel(int* __restrict__ counts) {
    int i = blockIdx.x * blockDim.x + threadIdx.x;
    if (i < N_NODES) counts[i] = 0;
}

__global__ void count_kernel(const int* __restrict__ ei, int* __restrict__ counts) {
    int e = blockIdx.x * blockDim.x + threadIdx.x;
    if (e < N_EDGES) atomicAdd(&counts[ei[N_EDGES + e]], 1);
}

__global__ __launch_bounds__(256) void scan_part_kernel(const int* __restrict__ counts,
                                                        int* __restrict__ excl,
                                                        int* __restrict__ bsums) {
    __shared__ int tsum[256];
    const int t = threadIdx.x;
    const int base = blockIdx.x * 1024 + t * 4;
    int v[4];
    int s = 0;
#pragma unroll
    for (int j = 0; j < 4; j++) {
        int idx = base + j;
        v[j] = (idx < N_NODES) ? counts[idx] : 0;
        s += v[j];
    }
    tsum[t] = s;
    __syncthreads();
    for (int off = 1; off < 256; off <<= 1) {
        int add = (t >= off) ? tsum[t - off] : 0;
        __syncthreads();
        tsum[t] += add;
        __syncthreads();
    }
    int run = tsum[t] - s;
#pragma unroll
    for (int j = 0; j < 4; j++) {
        int idx = base + j;
        if (idx < N_NODES) excl[idx] = run;
        run += v[j];
    }
    if (t == 255) bsums[blockIdx.x] = tsum[255];
}

// wave-parallel exclusive scan of the 49 block sums
__global__ void scan_sums_kernel(int* __restrict__ bsums) {
    int ln = threadIdx.x;  // 64 threads = 1 wave
    int v = (ln < SCAN_BLOCKS) ? bsums[ln] : 0;
    for (int off = 1; off < 64; off <<= 1) {
        int u = __shfl_up(v, off, 64);
        if (ln >= off) v += u;
    }
    int excl = __shfl_up(v, 1, 64);
    if (ln == 0) excl = 0;
    if (ln < SCAN_BLOCKS) bsums[ln] = excl;
}

__global__ void add_dinv_kernel(int* __restrict__ offsets, const int* __restrict__ bsums,
                                int* __restrict__ woff, const int* __restrict__ counts,
                                float* __restrict__ dinv) {
    int i = blockIdx.x * blockDim.x + threadIdx.x;
    if (i < N_NODES) {
        int o = offsets[i] + bsums[i >> 10];
        offsets[i] = o;
        woff[i] = o;
        dinv[i] = rsqrtf(1.0f + (float)counts[i]);
    }
    if (i == 0) offsets[N_NODES] = N_EDGES;
}

// edge record is just src (4B): norm is folded into prescaled rows (GEMM
// epilogues scale row r by dinv[r]) and the dst factor applied at gather end.
__global__ void fill_kernel(const int* __restrict__ ei, int* __restrict__ woff,
                            int* __restrict__ sedge) {
    int e = blockIdx.x * blockDim.x + threadIdx.x;
    if (e < N_EDGES) {
        int s = ei[e];
        int d = ei[N_EDGES + e];
        int pos = atomicAdd(&woff[d], 1);
        sedge[pos] = s;
    }
}

// ---------------------------------------------------------------- casts
// WT[n][k] = bf16(W[k][n]); grid covers N*K exactly
__global__ __launch_bounds__(256) void tcast_kernel(const float* __restrict__ W,
                                                    unsigned short* __restrict__ WT,
                                                    int K, int N) {
    int idx = blockIdx.x * 256 + threadIdx.x;
    int n = idx / K, k = idx - n * K;
    WT[idx] = f2bf(W[(size_t)k * N + n]);
}

// ------------------------------------------- fused cast+GEMM layer 1 (m97)
// H1[M,256](fp8) = fp8( dinv[row] * (bf16(x[M,512]) @ W1T[256,512]^T) )
// Proven R2 structure: 128x128 tile, BK=32, 4 waves (each 64x64 via 4x4 of
// 16x16x32 MFMA), B via global_load_lds. A-stage replaced by fp32 load +
// in-register bf16 cvt + ds_write (fuses away the cast_x pass; numerics
// identical: same RNE cast, same MFMA order).
__global__ __launch_bounds__(256) void gemm1_f32(const float* __restrict__ x,
                                                 const unsigned short* __restrict__ BT,
                                                 unsigned char* __restrict__ C,
                                                 const float* __restrict__ dinv) {
    __shared__ unsigned short As[128 * 32];  // [row][k] 64B rows
    __shared__ unsigned short Bs[128 * 32];

    const int tid = threadIdx.x;
    const int w = tid >> 6;
    const int ln = tid & 63;
    const int br = blockIdx.y * 128;
    const int bc = blockIdx.x * 128;

    const int quad = ln >> 4;
    const int l16 = ln & 15;
    const int wr = (w >> 1) * 64;
    const int wc = (w & 1) * 64;

    const int crow = ln >> 2;
    const int koff = (ln & 3) * 8;

    // A rows this thread stages (clamped; stores guarded)
    int row0 = br + (w + 0) * 16 + crow;
    int row1 = br + (w + 4) * 16 + crow;
    row0 = row0 < N_NODES ? row0 : N_NODES - 1;
    row1 = row1 < N_NODES ? row1 : N_NODES - 1;
    const float* xp0 = x + (size_t)row0 * IN_C + koff;
    const float* xp1 = x + (size_t)row1 * IN_C + koff;

    f32x4 acc[4][4];
#pragma unroll
    for (int mt = 0; mt < 4; mt++)
#pragma unroll
        for (int nt = 0; nt < 4; nt++) acc[mt][nt] = (f32x4){0.f, 0.f, 0.f, 0.f};

    for (int kk = 0; kk < IN_C; kk += 32) {
        // A: fp32 -> bf16 reg-staging (2 rows x 8 els per thread)
        float4 u0 = *(const float4*)(xp0 + kk);
        float4 u1 = *(const float4*)(xp0 + kk + 4);
        float4 u2 = *(const float4*)(xp1 + kk);
        float4 u3 = *(const float4*)(xp1 + kk + 4);
        // B: async global->LDS (rows = block cols, no clamp needed: N=256)
#pragma unroll
        for (int t = 0; t < 2; t++) {
            int c = w + t * 4;
            int rowb = bc + c * 16 + crow;
            const unsigned short* gp = BT + (size_t)rowb * IN_C + kk + koff;
            glds16(gp, Bs + c * 512 + ln * 8);
        }
        bf16x8 a0, a1;
        a0[0] = (short)f2bf(u0.x); a0[1] = (short)f2bf(u0.y);
        a0[2] = (short)f2bf(u0.z); a0[3] = (short)f2bf(u0.w);
        a0[4] = (short)f2bf(u1.x); a0[5] = (short)f2bf(u1.y);
        a0[6] = (short)f2bf(u1.z); a0[7] = (short)f2bf(u1.w);
        a1[0] = (short)f2bf(u2.x); a1[1] = (short)f2bf(u2.y);
        a1[2] = (short)f2bf(u2.z); a1[3] = (short)f2bf(u2.w);
        a1[4] = (short)f2bf(u3.x); a1[5] = (short)f2bf(u3.y);
        a1[6] = (short)f2bf(u3.z); a1[7] = (short)f2bf(u3.w);
        *(bf16x8*)&As[(w + 0) * 512 + ln * 8] = a0;
        *(bf16x8*)&As[(w + 4) * 512 + ln * 8] = a1;
        __syncthreads();

        bf16x8 af[4], bfr[4];
#pragma unroll
        for (int mt = 0; mt < 4; mt++)
            af[mt] = *(const bf16x8*)&As[(wr + mt * 16 + l16) * 32 + quad * 8];
#pragma unroll
        for (int nt = 0; nt < 4; nt++)
            bfr[nt] = *(const bf16x8*)&Bs[(wc + nt * 16 + l16) * 32 + quad * 8];
#pragma unroll
        for (int mt = 0; mt < 4; mt++)
#pragma unroll
            for (int nt = 0; nt < 4; nt++)
                acc[mt][nt] = __builtin_amdgcn_mfma_f32_16x16x32_bf16(af[mt], bfr[nt],
                                                                      acc[mt][nt], 0, 0, 0);
        __syncthreads();
    }

#pragma unroll
    for (int mt = 0; mt < 4; mt++) {
#pragma unroll
        for (int r = 0; r < 4; r++) {
            int gr = br + wr + mt * 16 + quad * 4 + r;
            if (gr < N_NODES) {
                float ds = dinv[gr];
#pragma unroll
                for (int nt = 0; nt < 4; nt++) {
                    int gc = bc + wc + nt * 16 + l16;
                    C[(size_t)gr * HID_C + gc] = f2fp8(ds * acc[mt][nt][r]);
                }
            }
        }
    }
}

// ------------------------------------------------------ GEMM layer 2 (2-ph)
// H2[M,128](bf16) = bf16( dinv[row] * (A1b[M,256](bf16) @ W2T[128,256]^T) )
// BM=64, BN=128 (full N -> A read once), BK=32, double-buffered, both
// operands via global_load_lds. Wave w: rows (w>>1)*32, cols (w&1)*64.
__global__ __launch_bounds__(256) void gemm2_db(const unsigned short* __restrict__ A,
                                                const unsigned short* __restrict__ BT,
                                                unsigned short* __restrict__ C,
                                                const float* __restrict__ dinv) {
    __shared__ unsigned short As[2][64 * 32];   // 2 x 4 KB
    __shared__ unsigned short Bs[2][128 * 32];  // 2 x 8 KB

    const int tid = threadIdx.x;
    const int w = tid >> 6;
    const int ln = tid & 63;
    const int br = blockIdx.x * 64;

    const int quad = ln >> 4;
    const int l16 = ln & 15;
    const int wr = (w >> 1) * 32;
    const int wc = (w & 1) * 64;

    const int ak = (tid & 3) * 8;
    const int trow = tid >> 2;  // 0..63

    int arow = br + trow;
    arow = arow < N_NODES ? arow : N_NODES - 1;  // clamp (stores guarded)
    const unsigned short* agp0 = A + (size_t)arow * HID_C + ak;

    f32x4 acc[2][4];
#pragma unroll
    for (int mt = 0; mt < 2; mt++)
#pragma unroll
        for (int nt = 0; nt < 4; nt++) acc[mt][nt] = (f32x4){0.f, 0.f, 0.f, 0.f};

    // prologue: stage k-step 0
    glds16(agp0, &As[0][tid * 8]);
#pragma unroll
    for (int tt = 0; tt < 2; tt++) {
        const unsigned short* gp = BT + (size_t)(trow + 64 * tt) * HID_C + ak;
        glds16(gp, &Bs[0][tt * 2048 + tid * 8]);
    }
    __syncthreads();

    for (int t = 0; t < 8; t++) {
        const int buf = t & 1;
        const int nxt = buf ^ 1;
        if (t < 7) {
            const int kk = (t + 1) * 32;
            glds16(agp0 + kk, &As[nxt][tid * 8]);
#pragma unroll
            for (int tt = 0; tt < 2; tt++) {
                const unsigned short* gp = BT + (size_t)(trow + 64 * tt) * HID_C + kk + ak;
                glds16(gp, &Bs[nxt][tt * 2048 + tid * 8]);
            }
        }

        bf16x8 af[2], bfr[4];
#pragma unroll
        for (int mt = 0; mt < 2; mt++)
            af[mt] = *(const bf16x8*)&As[buf][(wr + mt * 16 + l16) * 32 + quad * 8];
#pragma unroll
        for (int nt = 0; nt < 4; nt++)
            bfr[nt] = *(const bf16x8*)&Bs[buf][(wc + nt * 16 + l16) * 32 + quad * 8];
#pragma unroll
        for (int mt = 0; mt < 2; mt++)
#pragma unroll
            for (int nt = 0; nt < 4; nt++)
                acc[mt][nt] = __builtin_amdgcn_mfma_f32_16x16x32_bf16(af[mt], bfr[nt],
                                                                      acc[mt][nt], 0, 0, 0);
        __syncthreads();
    }

#pragma unroll
    for (int mt = 0; mt < 2; mt++) {
#pragma unroll
        for (int r = 0; r < 4; r++) {
            int gr = br + wr + mt * 16 + quad * 4 + r;
            if (gr < N_NODES) {
                float ds = dinv[gr];
#pragma unroll
                for (int nt = 0; nt < 4; nt++) {
                    int gc = wc + nt * 16 + l16;
                    C[(size_t)gr * OUT_C + gc] = f2bf(ds * acc[mt][nt][r]);
                }
            }
        }
    }
}

// ------------------------------------------------------- gather aggregation
// Layer-1 gather: H rows are fp8(e4m3), prescaled by dinv[src]. One wave per
// node, 2 groups of 32 lanes; lane covers 8 channels (8B fp8 load).
// out = bf16( relu( dinv[node] * (self' + sum_e row'[src]) + bias ) )
__global__ __launch_bounds__(256) void gather1_fp8(const int* __restrict__ offsets,
                                                   const int* __restrict__ sedge,
                                                   const unsigned char* __restrict__ H,
                                                   const float* __restrict__ dinv,
                                                   const float* __restrict__ bias,
                                                   unsigned short* __restrict__ out) {
    const int node = blockIdx.x * 4 + (threadIdx.x >> 6);
    if (node >= N_NODES) return;
    const int ln = threadIdx.x & 63;
    const int g = ln >> 5;   // 2 groups
    const int l = ln & 31;
    const int c0 = l * 8;

    float acc[8] = {};
    if (g == 0) {  // self term exactly once (row already has dinv[node] folded)
        uint2 d = *(const uint2*)&H[(size_t)node * HID_C + c0];
        acc_fp8x4((int)d.x, acc);
        acc_fp8x4((int)d.y, acc + 4);
    }

    int k = offsets[node] + g;
    const int k1 = offsets[node + 1];
    for (; k + 6 < k1; k += 8) {  // 4-deep unroll, group stride 2
        int s0 = sedge[k], s1 = sedge[k + 2], s2 = sedge[k + 4], s3 = sedge[k + 6];
        uint2 d0 = *(const uint2*)&H[(size_t)s0 * HID_C + c0];
        uint2 d1 = *(const uint2*)&H[(size_t)s1 * HID_C + c0];
        uint2 d2 = *(const uint2*)&H[(size_t)s2 * HID_C + c0];
        uint2 d3 = *(const uint2*)&H[(size_t)s3 * HID_C + c0];
        acc_fp8x4((int)d0.x, acc); acc_fp8x4((int)d0.y, acc + 4);
        acc_fp8x4((int)d1.x, acc); acc_fp8x4((int)d1.y, acc + 4);
        acc_fp8x4((int)d2.x, acc); acc_fp8x4((int)d2.y, acc + 4);
        acc_fp8x4((int)d3.x, acc); acc_fp8x4((int)d3.y, acc + 4);
    }
    for (; k < k1; k += 2) {
        int s0 = sedge[k];
        uint2 d0 = *(const uint2*)&H[(size_t)s0 * HID_C + c0];
        acc_fp8x4((int)d0.x, acc);
        acc_fp8x4((int)d0.y, acc + 4);
    }

    // combine the 2 group partials
#pragma unroll
    for (int j = 0; j < 8; j++) acc[j] += __shfl_xor(acc[j], 32, 64);

    if (g == 0) {
        const float di = dinv[node];
        bf16x8 o;
#pragma unroll
        for (int j = 0; j < 8; j++)
            o[j] = (short)f2bf(fmaxf(di * acc[j] + bias[c0 + j], 0.0f));
        *(bf16x8*)&out[(size_t)node * HID_C + c0] = o;
    }
}

// Layer-2 gather: H rows bf16, prescaled by dinv[src]. 4 groups of 16 lanes;
// lane covers 8 channels (16B bf16 load). fp32 output.
__global__ __launch_bounds__(256) void gather2_bf16(const int* __restrict__ offsets,
                                                    const int* __restrict__ sedge,
                                                    const unsigned short* __restrict__ H,
                                                    const float* __restrict__ dinv,
                                                    const float* __restrict__ bias,
                                                    float* __restrict__ out) {
    const int node = blockIdx.x * 4 + (threadIdx.x >> 6);
    if (node >= N_NODES) return;
    const int ln = threadIdx.x & 63;
    const int g = ln >> 4;   // 4 groups
    const int l = ln & 15;
    const int c0 = l * 8;

    float acc[8] = {};
    if (g == 0) {
        bf16x8 h = *(const bf16x8*)&H[(size_t)node * OUT_C + c0];
#pragma unroll
        for (int j = 0; j < 8; j++) acc[j] = bf2f((unsigned short)h[j]);
    }

    int k = offsets[node] + g;
    const int k1 = offsets[node + 1];
    for (; k + 12 < k1; k += 16) {  // 4-deep unroll, group stride 4
        int s0 = sedge[k], s1 = sedge[k + 4], s2 = sedge[k + 8], s3 = sedge[k + 12];
        bf16x8 h0 = *(const bf16x8*)&H[(size_t)s0 * OUT_C + c0];
        bf16x8 h1 = *(const bf16x8*)&H[(size_t)s1 * OUT_C + c0];
        bf16x8 h2 = *(const bf16x8*)&H[(size_t)s2 * OUT_C + c0];
        bf16x8 h3 = *(const bf16x8*)&H[(size_t)s3 * OUT_C + c0];
#pragma unroll
        for (int j = 0; j < 8; j++) {
            acc[j] += bf2f((unsigned short)h0[j]);
            acc[j] += bf2f((unsigned short)h1[j]);
            acc[j] += bf2f((unsigned short)h2[j]);
            acc[j] += bf2f((unsigned short)h3[j]);
        }
    }
    for (; k < k1; k += 4) {
        int s0 = sedge[k];
        bf16x8 h0 = *(const bf16x8*)&H[(size_t)s0 * OUT_C + c0];
#pragma unroll
        for (int j = 0; j < 8; j++) acc[j] += bf2f((unsigned short)h0[j]);
    }

#pragma unroll
    for (int m = 16; m < 64; m <<= 1) {
#pragma unroll
        for (int j = 0; j < 8; j++) acc[j] += __shfl_xor(acc[j], m, 64);
    }

    if (g == 0) {
        const float di = dinv[node];
        float o[8];
#pragma unroll
        for (int j = 0; j < 8; j++) o[j] = di * acc[j] + bias[c0 + j];
        *(float4*)&out[(size_t)node * OUT_C + c0] = make_float4(o[0], o[1], o[2], o[3]);
        *(float4*)&out[(size_t)node * OUT_C + c0 + 4] = make_float4(o[4], o[5], o[6], o[7]);
    }
}

// ---------------------------------------------------------------- launcher
extern "C" void kernel_launch(void* const* d_in, const int* in_sizes, int n_in,
                              void* d_out, int out_size, void* d_ws, size_t ws_size,
                              hipStream_t stream) {
    const float* x  = (const float*)d_in[0];
    const int*   ei = (const int*)d_in[1];
    const float* W1 = (const float*)d_in[2];
    const float* b1 = (const float*)d_in[3];
    const float* W2 = (const float*)d_in[4];
    const float* b2 = (const float*)d_in[5];
    float* out = (float*)d_out;

    // workspace layout (4-byte words), same as known-good R2 (68.3 MiB).
    int*   counts     = (int*)d_ws;                          // 50048
    int*   offsets    = counts + 50048;                      // 50052 (+sentinel)
    int*   woff       = offsets + 50052;                     // 50048
    int*   bsums      = woff + 50048;                        // 64
    float* dinv       = (float*)(bsums + 64);                // 50048
    int*   sedge      = (int*)(dinv + 50048);                // 800000 (src only)
    unsigned short* W1T = (unsigned short*)(sedge + 800000);          // 131072 sh
    unsigned short* W2T = W1T + 131072;                               // 32768 sh
    unsigned short* xb  = W2T + 32768;                                // 25.6M sh region
    unsigned char*  H1  = (unsigned char*)(xb + (size_t)N_NODES * IN_C);  // 12.8MB fp8
    unsigned short* A1b = xb;                                         // overlay (bf16)
    unsigned short* H2  = xb + (size_t)N_NODES * HID_C;               // overlay (bf16)

    // CSR build + norm
    zero_counts_kernel<<<(N_NODES + 255) / 256, 256, 0, stream>>>(counts);
    count_kernel<<<(N_EDGES + 255) / 256, 256, 0, stream>>>(ei, counts);
    scan_part_kernel<<<SCAN_BLOCKS, 256, 0, stream>>>(counts, offsets, bsums);
    scan_sums_kernel<<<1, 64, 0, stream>>>(bsums);
    add_dinv_kernel<<<(N_NODES + 255) / 256, 256, 0, stream>>>(offsets, bsums, woff, counts, dinv);
    fill_kernel<<<(N_EDGES + 255) / 256, 256, 0, stream>>>(ei, woff, sedge);

    // weight casts (tiny)
    tcast_kernel<<<(IN_C * HID_C) / 256, 256, 0, stream>>>(W1, W1T, IN_C, HID_C);
    tcast_kernel<<<(HID_C * OUT_C) / 256, 256, 0, stream>>>(W2, W2T, HID_C, OUT_C);

    // layer 1: H1 = fp8( dinv[row] * (bf16(x) @ W1T^T) )  (cast fused into A-stage)
    {
        dim3 grid(HID_C / 128, (N_NODES + 127) / 128);
        gemm1_f32<<<grid, 256, 0, stream>>>(x, W1T, H1, dinv);
    }
    gather1_fp8<<<(N_NODES + 3) / 4, 256, 0, stream>>>(offsets, sedge, H1, dinv, b1, A1b);

    // layer 2: H2 = bf16( dinv[row] * (A1b @ W2T^T) )
    gemm2_db<<<(N_NODES + 63) / 64, 256, 0, stream>>>(A1b, W2T, H2, dinv);
    gather2_bf16<<<(N_NODES + 3) / 4, 256, 0, stream>>>(offsets, sedge, H2, dinv, b2, out);
}

// Round 8
// 383.742 us; speedup vs baseline: 1.0397x; 1.0270x over previous
//
#include <hip/hip_runtime.h>
#include <hip/hip_bf16.h>

#define N_NODES 50000
#define N_EDGES 800000
#define IN_C 512
#define HID_C 256
#define OUT_C 128
#define SCAN_BLOCKS 49  // ceil(50000 / 1024)

typedef short bf16x8 __attribute__((ext_vector_type(8)));
typedef float f32x4 __attribute__((ext_vector_type(4)));
typedef float f32x2 __attribute__((ext_vector_type(2)));

__device__ __forceinline__ float bf2f(unsigned short u) {
    return __uint_as_float(((unsigned)u) << 16);
}
__device__ __forceinline__ unsigned short f2bf(float f) {
    __hip_bfloat16 h = __float2bfloat16(f);
    return *(unsigned short*)&h;
}
// decode 4 fp8(e4m3) from one dword, accumulate (unweighted) into a[0..3]
__device__ __forceinline__ void acc_fp8x4(int dw, float* a) {
    f32x2 lo = __builtin_amdgcn_cvt_pk_f32_fp8(dw, false);
    f32x2 hi = __builtin_amdgcn_cvt_pk_f32_fp8(dw, true);
    a[0] += lo[0]; a[1] += lo[1]; a[2] += hi[0]; a[3] += hi[1];
}
__device__ __forceinline__ unsigned char f2fp8(float f) {
    return (unsigned char)(__builtin_amdgcn_cvt_pk_fp8_f32(f, 0.0f, 0, false) & 0xff);
}
__device__ __forceinline__ void glds16(const void* gp, void* lp) {
    __builtin_amdgcn_global_load_lds((const __attribute__((address_space(1))) void*)gp,
                                     (__attribute__((address_space(3))) void*)lp, 16, 0, 0);
}

// ---------------------------------------------------------------- CSR build
__global__ void zero_counts_kernel(int* __restrict__ counts) {
    int i = blockIdx.x * blockDim.x + threadIdx.x;
    if (i < N_NODES) counts[i] = 0;
}

__global__ void count_kernel(const int* __restrict__ ei, int* __restrict__ counts) {
    int e = blockIdx.x * blockDim.x + threadIdx.x;
    if (e < N_EDGES) atomicAdd(&counts[ei[N_EDGES + e]], 1);
}

__global__ __launch_bounds__(256) void scan_part_kernel(const int* __restrict__ counts,
                                                        int* __restrict__ excl,
                                                        int* __restrict__ bsums) {
    __shared__ int tsum[256];
    const int t = threadIdx.x;
    const int base = blockIdx.x * 1024 + t * 4;
    int v[4];
    int s = 0;
#pragma unroll
    for (int j = 0; j < 4; j++) {
        int idx = base + j;
        v[j] = (idx < N_NODES) ? counts[idx] : 0;
        s += v[j];
    }
    tsum[t] = s;
    __syncthreads();
    for (int off = 1; off < 256; off <<= 1) {
        int add = (t >= off) ? tsum[t - off] : 0;
        __syncthreads();
        tsum[t] += add;
        __syncthreads();
    }
    int run = tsum[t] - s;
#pragma unroll
    for (int j = 0; j < 4; j++) {
        int idx = base + j;
        if (idx < N_NODES) excl[idx] = run;
        run += v[j];
    }
    if (t == 255) bsums[blockIdx.x] = tsum[255];
}

// wave-parallel exclusive scan of the 49 block sums
__global__ void scan_sums_kernel(int* __restrict__ bsums) {
    int ln = threadIdx.x;  // 64 threads = 1 wave
    int v = (ln < SCAN_BLOCKS) ? bsums[ln] : 0;
    for (int off = 1; off < 64; off <<= 1) {
        int u = __shfl_up(v, off, 64);
        if (ln >= off) v += u;
    }
    int excl = __shfl_up(v, 1, 64);
    if (ln == 0) excl = 0;
    if (ln < SCAN_BLOCKS) bsums[ln] = excl;
}

__global__ void add_dinv_kernel(int* __restrict__ offsets, const int* __restrict__ bsums,
                                int* __restrict__ woff, const int* __restrict__ counts,
                                float* __restrict__ dinv) {
    int i = blockIdx.x * blockDim.x + threadIdx.x;
    if (i < N_NODES) {
        int o = offsets[i] + bsums[i >> 10];
        offsets[i] = o;
        woff[i] = o;
        dinv[i] = rsqrtf(1.0f + (float)counts[i]);
    }
    if (i == 0) offsets[N_NODES] = N_EDGES;
}

// edge record is just src (4B): norm is folded into prescaled rows (GEMM
// epilogues scale row r by dinv[r]) and the dst factor applied at gather end.
__global__ void fill_kernel(const int* __restrict__ ei, int* __restrict__ woff,
                            int* __restrict__ sedge) {
    int e = blockIdx.x * blockDim.x + threadIdx.x;
    if (e < N_EDGES) {
        int s = ei[e];
        int d = ei[N_EDGES + e];
        int pos = atomicAdd(&woff[d], 1);
        sedge[pos] = s;
    }
}

// ---------------------------------------------------------------- casts
// WT[n][k] = bf16(W[k][n]); grid covers N*K exactly
__global__ __launch_bounds__(256) void tcast_kernel(const float* __restrict__ W,
                                                    unsigned short* __restrict__ WT,
                                                    int K, int N) {
    int idx = blockIdx.x * 256 + threadIdx.x;
    int n = idx / K, k = idx - n * K;
    WT[idx] = f2bf(W[(size_t)k * N + n]);
}

// ------------------------------------------- fused cast+GEMM layer 1 (m97)
// H1[M,256](fp8) = fp8( dinv[row] * (bf16(x[M,512]) @ W1T[256,512]^T) )
// 128x128 tile, BK=32, 4 waves. BOTH operands via global_load_lds (fully
// async staging, one vmcnt drain per step — the R2 critical path). A is
// staged as RAW FP32 (16 KB/step) and converted to bf16 on the READ side
// (fuses away cast_x). XOR-swizzled LDS (both-sides: pre-swizzled global
// source + swizzled read offset) kills the 16-way (A) / 8-way (B) bank
// conflicts: A -> 2-way (free), B -> 4-way.
__global__ __launch_bounds__(256) void gemm1_f32(const float* __restrict__ x,
                                                 const unsigned short* __restrict__ BT,
                                                 unsigned char* __restrict__ C,
                                                 const float* __restrict__ dinv) {
    __shared__ float As[128 * 32];           // fp32, phys = row*32 + (c ^ ((row&7)<<2))
    __shared__ unsigned short Bs[128 * 32];  // bf16, phys 16B-unit = row*4 + (u ^ (row&3))

    const int tid = threadIdx.x;
    const int w = tid >> 6;
    const int ln = tid & 63;
    const int br = blockIdx.y * 128;
    const int bc = blockIdx.x * 128;

    const int quad = ln >> 4;
    const int l16 = ln & 15;
    const int wr = (w >> 1) * 64;
    const int wc = (w & 1) * 64;

    // A staging: call i covers rows (i*4+w)*8 .. +8; lane ln -> row +(ln>>3),
    // pre-swizzled fp32 col 4*((ln&7)^(ln>>3)) (16B aligned, same 128B/row
    // coalescing as linear).
    const int arl = ln >> 3;
    const int acs = ((ln & 7) ^ arl) << 2;
    // B staging: call t, c=w+t*4 covers rows c*16 .. +16; lane ln -> row
    // +(ln>>2), pre-swizzled 8-short unit (ln&3)^((ln>>2)&3).
    const int brl = ln >> 2;
    const int bus = ((ln & 3) ^ (brl & 3)) << 3;

    f32x4 acc[4][4];
#pragma unroll
    for (int mt = 0; mt < 4; mt++)
#pragma unroll
        for (int nt = 0; nt < 4; nt++) acc[mt][nt] = (f32x4){0.f, 0.f, 0.f, 0.f};

    // read-side swizzled offsets
    const int r7 = l16 & 7;
    const int o1 = (quad << 3) ^ (r7 << 2);          // fp32-word offset in A row
    const int bso = (quad ^ (l16 & 3)) << 3;         // short offset in B row

    for (int kk = 0; kk < IN_C; kk += 32) {
        // A: 4 async calls (16 KB fp32), clamped rows (dup read, stores guarded)
#pragma unroll
        for (int i = 0; i < 4; i++) {
            int gr = br + (i * 4 + w) * 8 + arl;
            gr = gr < N_NODES ? gr : N_NODES - 1;
            const float* gp = x + (size_t)gr * IN_C + kk + acs;
            glds16(gp, (char*)As + (i * 4 + w) * 1024 + ln * 16);
        }
        // B: 2 async calls (8 KB bf16); N=256 so no clamp needed
#pragma unroll
        for (int t = 0; t < 2; t++) {
            int c = w + t * 4;
            int rowb = bc + c * 16 + brl;
            const unsigned short* gp = BT + (size_t)rowb * IN_C + kk + bus;
            glds16(gp, (char*)Bs + c * 1024 + ln * 16);
        }
        __syncthreads();

        bf16x8 af[4], bfr[4];
#pragma unroll
        for (int mt = 0; mt < 4; mt++) {
            int row = wr + mt * 16 + l16;
            const float* p = As + row * 32;
            float4 fa = *(const float4*)(p + o1);         // logical q*8+0..3
            float4 fb = *(const float4*)(p + (o1 ^ 4));   // logical q*8+4..7
            bf16x8 a8;
            a8[0] = (short)f2bf(fa.x); a8[1] = (short)f2bf(fa.y);
            a8[2] = (short)f2bf(fa.z); a8[3] = (short)f2bf(fa.w);
            a8[4] = (short)f2bf(fb.x); a8[5] = (short)f2bf(fb.y);
            a8[6] = (short)f2bf(fb.z); a8[7] = (short)f2bf(fb.w);
            af[mt] = a8;
        }
#pragma unroll
        for (int nt = 0; nt < 4; nt++) {
            int row = wc + nt * 16 + l16;
            bfr[nt] = *(const bf16x8*)&Bs[row * 32 + bso];
        }
#pragma unroll
        for (int mt = 0; mt < 4; mt++)
#pragma unroll
            for (int nt = 0; nt < 4; nt++)
                acc[mt][nt] = __builtin_amdgcn_mfma_f32_16x16x32_bf16(af[mt], bfr[nt],
                                                                      acc[mt][nt], 0, 0, 0);
        __syncthreads();
    }

#pragma unroll
    for (int mt = 0; mt < 4; mt++) {
#pragma unroll
        for (int r = 0; r < 4; r++) {
            int gr = br + wr + mt * 16 + quad * 4 + r;
            if (gr < N_NODES) {
                float ds = dinv[gr];
#pragma unroll
                for (int nt = 0; nt < 4; nt++) {
                    int gc = bc + wc + nt * 16 + l16;
                    C[(size_t)gr * HID_C + gc] = f2fp8(ds * acc[mt][nt][r]);
                }
            }
        }
    }
}

// ------------------------------------------------------ GEMM layer 2 (2-ph)
// H2[M,128](bf16) = bf16( dinv[row] * (A1b[M,256](bf16) @ W2T[128,256]^T) )
// BM=64, BN=128 (full N -> A read once), BK=32, double-buffered, both
// operands via global_load_lds. Wave w: rows (w>>1)*32, cols (w&1)*64.
__global__ __launch_bounds__(256) void gemm2_db(const unsigned short* __restrict__ A,
                                                const unsigned short* __restrict__ BT,
                                                unsigned short* __restrict__ C,
                                                const float* __restrict__ dinv) {
    __shared__ unsigned short As[2][64 * 32];   // 2 x 4 KB
    __shared__ unsigned short Bs[2][128 * 32];  // 2 x 8 KB

    const int tid = threadIdx.x;
    const int w = tid >> 6;
    const int ln = tid & 63;
    const int br = blockIdx.x * 64;

    const int quad = ln >> 4;
    const int l16 = ln & 15;
    const int wr = (w >> 1) * 32;
    const int wc = (w & 1) * 64;

    const int ak = (tid & 3) * 8;
    const int trow = tid >> 2;  // 0..63

    int arow = br + trow;
    arow = arow < N_NODES ? arow : N_NODES - 1;  // clamp (stores guarded)
    const unsigned short* agp0 = A + (size_t)arow * HID_C + ak;

    f32x4 acc[2][4];
#pragma unroll
    for (int mt = 0; mt < 2; mt++)
#pragma unroll
        for (int nt = 0; nt < 4; nt++) acc[mt][nt] = (f32x4){0.f, 0.f, 0.f, 0.f};

    // prologue: stage k-step 0
    glds16(agp0, &As[0][tid * 8]);
#pragma unroll
    for (int tt = 0; tt < 2; tt++) {
        const unsigned short* gp = BT + (size_t)(trow + 64 * tt) * HID_C + ak;
        glds16(gp, &Bs[0][tt * 2048 + tid * 8]);
    }
    __syncthreads();

    for (int t = 0; t < 8; t++) {
        const int buf = t & 1;
        const int nxt = buf ^ 1;
        if (t < 7) {
            const int kk = (t + 1) * 32;
            glds16(agp0 + kk, &As[nxt][tid * 8]);
#pragma unroll
            for (int tt = 0; tt < 2; tt++) {
                const unsigned short* gp = BT + (size_t)(trow + 64 * tt) * HID_C + kk + ak;
                glds16(gp, &Bs[nxt][tt * 2048 + tid * 8]);
            }
        }

        bf16x8 af[2], bfr[4];
#pragma unroll
        for (int mt = 0; mt < 2; mt++)
            af[mt] = *(const bf16x8*)&As[buf][(wr + mt * 16 + l16) * 32 + quad * 8];
#pragma unroll
        for (int nt = 0; nt < 4; nt++)
            bfr[nt] = *(const bf16x8*)&Bs[buf][(wc + nt * 16 + l16) * 32 + quad * 8];
#pragma unroll
        for (int mt = 0; mt < 2; mt++)
#pragma unroll
            for (int nt = 0; nt < 4; nt++)
                acc[mt][nt] = __builtin_amdgcn_mfma_f32_16x16x32_bf16(af[mt], bfr[nt],
                                                                      acc[mt][nt], 0, 0, 0);
        __syncthreads();
    }

#pragma unroll
    for (int mt = 0; mt < 2; mt++) {
#pragma unroll
        for (int r = 0; r < 4; r++) {
            int gr = br + wr + mt * 16 + quad * 4 + r;
            if (gr < N_NODES) {
                float ds = dinv[gr];
#pragma unroll
                for (int nt = 0; nt < 4; nt++) {
                    int gc = wc + nt * 16 + l16;
                    C[(size_t)gr * OUT_C + gc] = f2bf(ds * acc[mt][nt][r]);
                }
            }
        }
    }
}

// ------------------------------------------------------- gather aggregation
// Layer-1 gather: H rows are fp8(e4m3), prescaled by dinv[src]. One wave per
// node, 2 groups of 32 lanes; lane covers 8 channels (8B fp8 load).
// out = bf16( relu( dinv[node] * (self' + sum_e row'[src]) + bias ) )
__global__ __launch_bounds__(256) void gather1_fp8(const int* __restrict__ offsets,
                                                   const int* __restrict__ sedge,
                                                   const unsigned char* __restrict__ H,
                                                   const float* __restrict__ dinv,
                                                   const float* __restrict__ bias,
                                                   unsigned short* __restrict__ out) {
    const int node = blockIdx.x * 4 + (threadIdx.x >> 6);
    if (node >= N_NODES) return;
    const int ln = threadIdx.x & 63;
    const int g = ln >> 5;   // 2 groups
    const int l = ln & 31;
    const int c0 = l * 8;

    float acc[8] = {};
    if (g == 0) {  // self term exactly once (row already has dinv[node] folded)
        uint2 d = *(const uint2*)&H[(size_t)node * HID_C + c0];
        acc_fp8x4((int)d.x, acc);
        acc_fp8x4((int)d.y, acc + 4);
    }

    int k = offsets[node] + g;
    const int k1 = offsets[node + 1];
    for (; k + 6 < k1; k += 8) {  // 4-deep unroll, group stride 2
        int s0 = sedge[k], s1 = sedge[k + 2], s2 = sedge[k + 4], s3 = sedge[k + 6];
        uint2 d0 = *(const uint2*)&H[(size_t)s0 * HID_C + c0];
        uint2 d1 = *(const uint2*)&H[(size_t)s1 * HID_C + c0];
        uint2 d2 = *(const uint2*)&H[(size_t)s2 * HID_C + c0];
        uint2 d3 = *(const uint2*)&H[(size_t)s3 * HID_C + c0];
        acc_fp8x4((int)d0.x, acc); acc_fp8x4((int)d0.y, acc + 4);
        acc_fp8x4((int)d1.x, acc); acc_fp8x4((int)d1.y, acc + 4);
        acc_fp8x4((int)d2.x, acc); acc_fp8x4((int)d2.y, acc + 4);
        acc_fp8x4((int)d3.x, acc); acc_fp8x4((int)d3.y, acc + 4);
    }
    for (; k < k1; k += 2) {
        int s0 = sedge[k];
        uint2 d0 = *(const uint2*)&H[(size_t)s0 * HID_C + c0];
        acc_fp8x4((int)d0.x, acc);
        acc_fp8x4((int)d0.y, acc + 4);
    }

    // combine the 2 group partials
#pragma unroll
    for (int j = 0; j < 8; j++) acc[j] += __shfl_xor(acc[j], 32, 64);

    if (g == 0) {
        const float di = dinv[node];
        bf16x8 o;
#pragma unroll
        for (int j = 0; j < 8; j++)
            o[j] = (short)f2bf(fmaxf(di * acc[j] + bias[c0 + j], 0.0f));
        *(bf16x8*)&out[(size_t)node * HID_C + c0] = o;
    }
}

// Layer-2 gather: H rows bf16, prescaled by dinv[src]. 4 groups of 16 lanes;
// lane covers 8 channels (16B bf16 load). fp32 output.
__global__ __launch_bounds__(256) void gather2_bf16(const int* __restrict__ offsets,
                                                    const int* __restrict__ sedge,
                                                    const unsigned short* __restrict__ H,
                                                    const float* __restrict__ dinv,
                                                    const float* __restrict__ bias,
                                                    float* __restrict__ out) {
    const int node = blockIdx.x * 4 + (threadIdx.x >> 6);
    if (node >= N_NODES) return;
    const int ln = threadIdx.x & 63;
    const int g = ln >> 4;   // 4 groups
    const int l = ln & 15;
    const int c0 = l * 8;

    float acc[8] = {};
    if (g == 0) {
        bf16x8 h = *(const bf16x8*)&H[(size_t)node * OUT_C + c0];
#pragma unroll
        for (int j = 0; j < 8; j++) acc[j] = bf2f((unsigned short)h[j]);
    }

    int k = offsets[node] + g;
    const int k1 = offsets[node + 1];
    for (; k + 12 < k1; k += 16) {  // 4-deep unroll, group stride 4
        int s0 = sedge[k], s1 = sedge[k + 4], s2 = sedge[k + 8], s3 = sedge[k + 12];
        bf16x8 h0 = *(const bf16x8*)&H[(size_t)s0 * OUT_C + c0];
        bf16x8 h1 = *(const bf16x8*)&H[(size_t)s1 * OUT_C + c0];
        bf16x8 h2 = *(const bf16x8*)&H[(size_t)s2 * OUT_C + c0];
        bf16x8 h3 = *(const bf16x8*)&H[(size_t)s3 * OUT_C + c0];
#pragma unroll
        for (int j = 0; j < 8; j++) {
            acc[j] += bf2f((unsigned short)h0[j]);
            acc[j] += bf2f((unsigned short)h1[j]);
            acc[j] += bf2f((unsigned short)h2[j]);
            acc[j] += bf2f((unsigned short)h3[j]);
        }
    }
    for (; k < k1; k += 4) {
        int s0 = sedge[k];
        bf16x8 h0 = *(const bf16x8*)&H[(size_t)s0 * OUT_C + c0];
#pragma unroll
        for (int j = 0; j < 8; j++) acc[j] += bf2f((unsigned short)h0[j]);
    }

#pragma unroll
    for (int m = 16; m < 64; m <<= 1) {
#pragma unroll
        for (int j = 0; j < 8; j++) acc[j] += __shfl_xor(acc[j], m, 64);
    }

    if (g == 0) {
        const float di = dinv[node];
        float o[8];
#pragma unroll
        for (int j = 0; j < 8; j++) o[j] = di * acc[j] + bias[c0 + j];
        *(float4*)&out[(size_t)node * OUT_C + c0] = make_float4(o[0], o[1], o[2], o[3]);
        *(float4*)&out[(size_t)node * OUT_C + c0 + 4] = make_float4(o[4], o[5], o[6], o[7]);
    }
}

// ---------------------------------------------------------------- launcher
extern "C" void kernel_launch(void* const* d_in, const int* in_sizes, int n_in,
                              void* d_out, int out_size, void* d_ws, size_t ws_size,
                              hipStream_t stream) {
    const float* x  = (const float*)d_in[0];
    const int*   ei = (const int*)d_in[1];
    const float* W1 = (const float*)d_in[2];
    const float* b1 = (const float*)d_in[3];
    const float* W2 = (const float*)d_in[4];
    const float* b2 = (const float*)d_in[5];
    float* out = (float*)d_out;

    // workspace layout (4-byte words), same as known-good R2 (68.3 MiB).
    int*   counts     = (int*)d_ws;                          // 50048
    int*   offsets    = counts + 50048;                      // 50052 (+sentinel)
    int*   woff       = offsets + 50052;                     // 50048
    int*   bsums      = woff + 50048;                        // 64
    float* dinv       = (float*)(bsums + 64);                // 50048
    int*   sedge      = (int*)(dinv + 50048);                // 800000 (src only)
    unsigned short* W1T = (unsigned short*)(sedge + 800000);          // 131072 sh
    unsigned short* W2T = W1T + 131072;                               // 32768 sh
    unsigned short* xb  = W2T + 32768;                                // 25.6M sh region
    unsigned char*  H1  = (unsigned char*)(xb + (size_t)N_NODES * IN_C);  // 12.8MB fp8
    unsigned short* A1b = xb;                                         // overlay (bf16)
    unsigned short* H2  = xb + (size_t)N_NODES * HID_C;               // overlay (bf16)

    // CSR build + norm
    zero_counts_kernel<<<(N_NODES + 255) / 256, 256, 0, stream>>>(counts);
    count_kernel<<<(N_EDGES + 255) / 256, 256, 0, stream>>>(ei, counts);
    scan_part_kernel<<<SCAN_BLOCKS, 256, 0, stream>>>(counts, offsets, bsums);
    scan_sums_kernel<<<1, 64, 0, stream>>>(bsums);
    add_dinv_kernel<<<(N_NODES + 255) / 256, 256, 0, stream>>>(offsets, bsums, woff, counts, dinv);
    fill_kernel<<<(N_EDGES + 255) / 256, 256, 0, stream>>>(ei, woff, sedge);

    // weight casts (tiny)
    tcast_kernel<<<(IN_C * HID_C) / 256, 256, 0, stream>>>(W1, W1T, IN_C, HID_C);
    tcast_kernel<<<(HID_C * OUT_C) / 256, 256, 0, stream>>>(W2, W2T, HID_C, OUT_C);

    // layer 1: H1 = fp8( dinv[row] * (bf16(x) @ W1T^T) )  (async fp32 A staging)
    {
        dim3 grid(HID_C / 128, (N_NODES + 127) / 128);
        gemm1_f32<<<grid, 256, 0, stream>>>(x, W1T, H1, dinv);
    }
    gather1_fp8<<<(N_NODES + 3) / 4, 256, 0, stream>>>(offsets, sedge, H1, dinv, b1, A1b);

    // layer 2: H2 = bf16( dinv[row] * (A1b @ W2T^T) )
    gemm2_db<<<(N_NODES + 63) / 64, 256, 0, stream>>>(A1b, W2T, H2, dinv);
    gather2_bf16<<<(N_NODES + 3) / 4, 256, 0, stream>>>(offsets, sedge, H2, dinv, b2, out);
}